// Round 7
// baseline (2922.591 us; speedup 1.0000x reference)
//
#include <hip/hip_runtime.h>
#include <math.h>

#define BSZ 4
#define NN 1024
#define BH 8
#define DD 64
#define MM 2048
#define KRET 16
#define CC 64
#define NEGV -1000000000.0f
#define EPSV 1e-8f
#define SMAXV 4.0f
#define BUDGETV 512.0f

#define FMA4(a4, b4, acc) \
    fmaf((a4).w, (b4).w, fmaf((a4).z, (b4).z, fmaf((a4).y, (b4).y, fmaf((a4).x, (b4).x, (acc)))))

// ws layout (float-element offsets)
#define WS_NOV  0         // [32][1024] novelty
#define WS_CI   32768     // int [32][64] candidate indices
#define WS_CW   34816     // [32][64] cand_weight
#define WS_CKN  36864     // [32][64][64] unit-normalized cand_K
#define WS_CV   167936    // [32][64][64] cand_V
#define WS_PMAX 299008    // [32][64][16] slot-softmax partial max
#define WS_PSUM 331776    // [32][64][16] slot-softmax partial sumexp
#define WS_TOTS 364544    // [32] new_S totals (memset to 0 each call)

typedef _Float16 h2v __attribute__((ext_vector_type(2)));

__device__ __forceinline__ float dot8h(const uint4 a, const uint4 b, float c)
{
#if __has_builtin(__builtin_amdgcn_fdot2)
    c = __builtin_amdgcn_fdot2(__builtin_bit_cast(h2v, a.x), __builtin_bit_cast(h2v, b.x), c, false);
    c = __builtin_amdgcn_fdot2(__builtin_bit_cast(h2v, a.y), __builtin_bit_cast(h2v, b.y), c, false);
    c = __builtin_amdgcn_fdot2(__builtin_bit_cast(h2v, a.z), __builtin_bit_cast(h2v, b.z), c, false);
    c = __builtin_amdgcn_fdot2(__builtin_bit_cast(h2v, a.w), __builtin_bit_cast(h2v, b.w), c, false);
#else
    const h2v ax = __builtin_bit_cast(h2v, a.x), bx = __builtin_bit_cast(h2v, b.x);
    const h2v ay = __builtin_bit_cast(h2v, a.y), by = __builtin_bit_cast(h2v, b.y);
    const h2v az = __builtin_bit_cast(h2v, a.z), bz = __builtin_bit_cast(h2v, b.z);
    const h2v aw = __builtin_bit_cast(h2v, a.w), bw = __builtin_bit_cast(h2v, b.w);
    c = fmaf((float)ax[0], (float)bx[0], c); c = fmaf((float)ax[1], (float)bx[1], c);
    c = fmaf((float)ay[0], (float)by[0], c); c = fmaf((float)ay[1], (float)by[1], c);
    c = fmaf((float)az[0], (float)bz[0], c); c = fmaf((float)az[1], (float)bz[1], c);
    c = fmaf((float)aw[0], (float)bw[0], c); c = fmaf((float)aw[1], (float)bw[1], c);
#endif
    return c;
}

__device__ __forceinline__ unsigned pk2h(float a, float b)
{
#if __has_builtin(__builtin_amdgcn_cvt_pkrtz)
    return __builtin_bit_cast(unsigned, __builtin_amdgcn_cvt_pkrtz(a, b));
#else
    const unsigned short ua = __builtin_bit_cast(unsigned short, (_Float16)a);
    const unsigned short ub = __builtin_bit_cast(unsigned short, (_Float16)b);
    return (unsigned)ua | ((unsigned)ub << 16);
#endif
}

// ---------------------------------------------------------------------------
// Kernel 0: convert emK (f32) -> f16 into scratch (outV region; k3c rewrites
// outV later). 4M elements, 8 per thread.
// ---------------------------------------------------------------------------
__global__ __launch_bounds__(256)
void k0_cvt(const float* __restrict__ emK, unsigned short* __restrict__ Kh)
{
    const size_t base = ((size_t)blockIdx.x*256 + threadIdx.x)*8;
    const float4 a = *(const float4*)&emK[base];
    const float4 b = *(const float4*)&emK[base + 4];
    uint4 o;
    o.x = pk2h(a.x, a.y); o.y = pk2h(a.z, a.w);
    o.z = pk2h(b.x, b.y); o.w = pk2h(b.z, b.w);
    *(uint4*)&Kh[base] = o;
}

// ---------------------------------------------------------------------------
// Kernel 1 (R9): f16 SCREEN + f32 RESCORE.
// Six rounds showed only inst/byte-count cuts pay (R3/R6 ~1:1); structure
// experiments (occupancy/dbuf/barriers) were null. So halve the mass:
// screen dots via v_dot2_f32_f16 (2 MAC/inst, f32 accum, err<=~5e-3 vs
// top-16 spacing ~0.11), f16 LDS tiles (K-reads 128->64, q 64->32/tile,
// LDS 52.7->28KB). Then EXACT epilogue: approx top-24 indices -> f32
// rescore -> exact top-16/softmax/PV; novelty via per-lane top-4 tracker
// -> f32 rescore -> exact max. Final outputs are full-precision exact.
// ---------------------------------------------------------------------------
__global__ __launch_bounds__(256, 2)
void k1_read(const float* __restrict__ q, const float* __restrict__ qn,
             const float* __restrict__ surprise, const float* __restrict__ wnov,
             const float* __restrict__ emK, const unsigned short* __restrict__ Kh,
             const float* __restrict__ emV, const float* __restrict__ emS,
             float* __restrict__ out, float* __restrict__ ws)
{
    const int sb = blockIdx.x;            // 0..31  (s*8+b)
    const int s = sb >> 3, b = sb & 7;
    const int n0 = blockIdx.y << 6;       // n-tile of 64
    const int t = threadIdx.x;
    const int rg = t >> 3;                // row-group 0..31
    const int cg = t & 7;                 // col sub-lane 0..7
    const int r0 = rg << 1;               // this thread's 2 rows

    __shared__ unsigned short qh [64][72];   // f16, row stride 144B (=16*9: b128-aligned, +4 banks/row)
    __shared__ unsigned short qnh[64][72];
    __shared__ unsigned short Kth[64][72];
    __shared__ float Sm[64];

    // stage q / q_nov tile as f16 (on-the-fly convert)
    #pragma unroll
    for (int k = 0; k < 4; ++k) {
        const int fi = t + (k << 8);
        const int row = fi >> 4;
        const int col = (fi & 15) << 2;
        const size_t qb = (((size_t)s*NN + n0 + row)*BH + b)*DD + col;
        const float4 v  = *(const float4*)&q[qb];
        const float4 w4 = *(const float4*)&qn[qb];
        *(uint2*)&qh [row][col] = make_uint2(pk2h(v.x,  v.y),  pk2h(v.z,  v.w));
        *(uint2*)&qnh[row][col] = make_uint2(pk2h(w4.x, w4.y), pk2h(w4.z, w4.w));
    }

    // per-lane sorted-desc approx top-16 score lists + top-4 novelty trackers
    float lv[2][16]; int li[2][16];
    float nv[2][4];  int ni[2][4];
    #pragma unroll
    for (int rr = 0; rr < 2; ++rr) {
        #pragma unroll
        for (int i = 0; i < 16; ++i) { lv[rr][i] = -3.0e38f; li[rr][i] = 0; }
        #pragma unroll
        for (int i = 0; i < 4; ++i)  { nv[rr][i] = -3.0e38f; ni[rr][i] = 0; }
    }

    const unsigned short* Khb = Kh + (size_t)sb*MM*DD;
    const float* Sb = emS + (size_t)sb*MM;

#define CEB(x, y) { const bool sw_ = bv[y] > bv[x];                       \
    const float f0_ = sw_ ? bv[y] : bv[x]; const float f1_ = sw_ ? bv[x] : bv[y]; \
    bv[x] = f0_; bv[y] = f1_;                                             \
    const int i0_ = sw_ ? bi[y] : bi[x]; const int i1_ = sw_ ? bi[x] : bi[y]; \
    bi[x] = i0_; bi[y] = i1_; }
#define CEL(x, y) { const bool sw_ = lv[rr][y] > lv[rr][x];               \
    const float f0_ = sw_ ? lv[rr][y] : lv[rr][x];                        \
    const float f1_ = sw_ ? lv[rr][x] : lv[rr][y];                        \
    lv[rr][x] = f0_; lv[rr][y] = f1_;                                     \
    const int i0_ = sw_ ? li[rr][y] : li[rr][x];                          \
    const int i1_ = sw_ ? li[rr][x] : li[rr][y];                          \
    li[rr][x] = i0_; li[rr][y] = i1_; }

    #pragma unroll 1
    for (int mt = 0; mt < MM/64; ++mt) {
        __syncthreads();
        #pragma unroll
        for (int k = 0; k < 2; ++k) {
            const int fi = t + (k << 8);
            const int row = fi >> 3;
            const int col8 = (fi & 7) << 3;
            *(uint4*)&Kth[row][col8] =
                *(const uint4*)&Khb[((size_t)(mt*64 + row))*DD + col8];
        }
        if (t < 64) Sm[t] = Sb[mt*64 + t];
        __syncthreads();

        float acc[2][8], accn[2][8];
        #pragma unroll
        for (int rr = 0; rr < 2; ++rr)
            #pragma unroll
            for (int j = 0; j < 8; ++j) { acc[rr][j] = 0.f; accn[rr][j] = 0.f; }

        #pragma unroll
        for (int ch = 0; ch < 8; ++ch) {
            const uint4 qa  = *(const uint4*)&qh [r0][ch << 3];
            const uint4 na  = *(const uint4*)&qnh[r0][ch << 3];
            const uint4 qb4 = *(const uint4*)&qh [r0 + 1][ch << 3];
            const uint4 nb4 = *(const uint4*)&qnh[r0 + 1][ch << 3];
            #pragma unroll
            for (int j = 0; j < 8; ++j) {
                const uint4 k8 = *(const uint4*)&Kth[cg + (j << 3)][ch << 3];
                acc[0][j]  = dot8h(qa,  k8, acc[0][j]);
                accn[0][j] = dot8h(na,  k8, accn[0][j]);
                acc[1][j]  = dot8h(qb4, k8, acc[1][j]);
                accn[1][j] = dot8h(nb4, k8, accn[1][j]);
            }
        }

        float sq[2][8], sn[2][8];
        #pragma unroll
        for (int j = 0; j < 8; ++j) {
            const int ml = cg + (j << 3);
            const bool act = Sm[ml] > 0.f;
            sq[0][j] = act ? acc[0][j] : NEGV;
            sq[1][j] = act ? acc[1][j] : NEGV;
            sn[0][j] = act ? accn[0][j] : -1.0f;
            sn[1][j] = act ? accn[1][j] : -1.0f;
        }

        #pragma unroll
        for (int rr = 0; rr < 2; ++rr) {
            // novelty: tile-best -> sorted-4 tracker
            float bn = sn[rr][0]; int bji = 0;
            #pragma unroll
            for (int j = 1; j < 8; ++j)
                if (sn[rr][j] > bn) { bn = sn[rr][j]; bji = j; }
            if (bn > nv[rr][3]) {
                const int bgi = mt*64 + cg + (bji << 3);
                if (bn > nv[rr][1]) {
                    nv[rr][3] = nv[rr][2]; ni[rr][3] = ni[rr][2];
                    nv[rr][2] = nv[rr][1]; ni[rr][2] = ni[rr][1];
                    if (bn > nv[rr][0]) {
                        nv[rr][1] = nv[rr][0]; ni[rr][1] = ni[rr][0];
                        nv[rr][0] = bn; ni[rr][0] = bgi;
                    } else { nv[rr][1] = bn; ni[rr][1] = bgi; }
                } else if (bn > nv[rr][2]) {
                    nv[rr][3] = nv[rr][2]; ni[rr][3] = ni[rr][2];
                    nv[rr][2] = bn; ni[rr][2] = bgi;
                } else { nv[rr][3] = bn; ni[rr][3] = bgi; }
            }

            // score batch top-16 merge (proven network from R5/R6)
            float bmax = sq[rr][0];
            #pragma unroll
            for (int j = 1; j < 8; ++j) bmax = fmaxf(bmax, sq[rr][j]);
            if (bmax > lv[rr][15]) {
                float bv[8]; int bi[8];
                #pragma unroll
                for (int j = 0; j < 8; ++j) {
                    bv[j] = sq[rr][j];
                    bi[j] = mt*64 + cg + (j << 3);
                }
                CEB(0,1) CEB(2,3) CEB(4,5) CEB(6,7)
                CEB(0,2) CEB(1,3) CEB(4,6) CEB(5,7)
                CEB(1,2) CEB(5,6)
                CEB(0,4) CEB(1,5) CEB(2,6) CEB(3,7)
                CEB(2,4) CEB(3,5)
                CEB(1,2) CEB(3,4) CEB(5,6)
                #pragma unroll
                for (int i = 0; i < 8; ++i) {
                    const bool tk = bv[7-i] > lv[rr][8+i];
                    if (tk) { lv[rr][8+i] = bv[7-i]; li[rr][8+i] = bi[7-i]; }
                }
                CEL(8,12) CEL(9,13) CEL(10,14) CEL(11,15)
                CEL(8,10) CEL(9,11) CEL(12,14) CEL(13,15)
                CEL(8,9)  CEL(10,11) CEL(12,13) CEL(14,15)
                CEL(0,15) CEL(1,14) CEL(2,13) CEL(3,12)
                CEL(4,11) CEL(5,10) CEL(6,9)  CEL(7,8)
                CEL(0,4) CEL(1,5) CEL(2,6) CEL(3,7)
                CEL(0,2) CEL(1,3) CEL(4,6) CEL(5,7)
                CEL(0,1) CEL(2,3) CEL(4,5) CEL(6,7)
                CEL(8,12) CEL(9,13) CEL(10,14) CEL(11,15)
                CEL(8,10) CEL(9,11) CEL(12,14) CEL(13,15)
                CEL(8,9)  CEL(10,11) CEL(12,13) CEL(14,15)
            }
        }
    }
#undef CEB
#undef CEL

    const float* Vb = emV + (size_t)sb*MM*DD;
    const float* Kb = emK + (size_t)sb*MM*DD;

    #pragma unroll 1
    for (int rr = 0; rr < 2; ++rr) {
        // ---- Phase A: approx global top-24 indices (3 per lane) ----
        int ikA = 0, ikB = 0, ikC = 0;
        #pragma unroll 1
        for (int k = 0; k < 24; ++k) {
            float cb = lv[rr][0]; int ci2 = li[rr][0]; int key = cg;
            #pragma unroll
            for (int off = 4; off >= 1; off >>= 1) {
                const float ov = __shfl_xor(cb, off, 8);
                const int   ok = __shfl_xor(key, off, 8);
                const int   oi = __shfl_xor(ci2, off, 8);
                if (ov > cb || (ov == cb && ok < key)) { cb = ov; key = ok; ci2 = oi; }
            }
            if (key == cg) {
                #pragma unroll
                for (int i = 0; i < 15; ++i) { lv[rr][i] = lv[rr][i+1]; li[rr][i] = li[rr][i+1]; }
                lv[rr][15] = -3.0e38f;   // prevent duplicate re-pop past list depth
            }
            if ((k & 7) == cg) {
                if (k < 8) ikA = ci2; else if (k < 16) ikB = ci2; else ikC = ci2;
            }
        }

        // ---- Phase B: exact f32 rescore (3 score + 4 novelty per lane) ----
        const float* qrow  = q  + (((size_t)s*NN + n0 + r0 + rr)*BH + b)*DD;
        const float* qnrow = qn + (((size_t)s*NN + n0 + r0 + rr)*BH + b)*DD;
        const float* kA = Kb + (size_t)ikA*DD;
        const float* kB = Kb + (size_t)ikB*DD;
        const float* kC = Kb + (size_t)ikC*DD;
        const float* p1 = Kb + (size_t)ni[rr][0]*DD;
        const float* p2 = Kb + (size_t)ni[rr][1]*DD;
        const float* p3 = Kb + (size_t)ni[rr][2]*DD;
        const float* p4 = Kb + (size_t)ni[rr][3]*DD;
        float eA = 0.f, eB = 0.f, eC = 0.f, f1 = 0.f, f2 = 0.f, f3 = 0.f, f4 = 0.f;
        #pragma unroll
        for (int c2 = 0; c2 < 16; ++c2) {
            const float4 qv  = *(const float4*)&qrow[c2 << 2];
            const float4 nqv = *(const float4*)&qnrow[c2 << 2];
            eA = FMA4(qv,  *(const float4*)&kA[c2 << 2], eA);
            eB = FMA4(qv,  *(const float4*)&kB[c2 << 2], eB);
            eC = FMA4(qv,  *(const float4*)&kC[c2 << 2], eC);
            f1 = FMA4(nqv, *(const float4*)&p1[c2 << 2], f1);
            f2 = FMA4(nqv, *(const float4*)&p2[c2 << 2], f2);
            f3 = FMA4(nqv, *(const float4*)&p3[c2 << 2], f3);
            f4 = FMA4(nqv, *(const float4*)&p4[c2 << 2], f4);
        }
        float ex[3]; int exi[3];
        ex[0] = (Sb[ikA] > 0.f) ? eA : NEGV;  exi[0] = ikA;
        ex[1] = (Sb[ikB] > 0.f) ? eB : NEGV;  exi[1] = ikB;
        ex[2] = (Sb[ikC] > 0.f) ? eC : NEGV;  exi[2] = ikC;
        const float xn = fmaxf(
            fmaxf((Sb[ni[rr][0]] > 0.f) ? f1 : -1.0f, (Sb[ni[rr][1]] > 0.f) ? f2 : -1.0f),
            fmaxf((Sb[ni[rr][2]] > 0.f) ? f3 : -1.0f, (Sb[ni[rr][3]] > 0.f) ? f4 : -1.0f));

        // ---- Phase C: exact top-16 of 24 + softmax + P.V ----
        float m0 = 0.f, den = 0.f, wkA2 = 0.f, wkB2 = 0.f;
        int ikx = 0, iky = 0;
        #pragma unroll 1
        for (int k = 0; k < 16; ++k) {
            float cb = ex[0]; int ci2 = exi[0];
            if (ex[1] > cb || (ex[1] == cb && exi[1] < ci2)) { cb = ex[1]; ci2 = exi[1]; }
            if (ex[2] > cb || (ex[2] == cb && exi[2] < ci2)) { cb = ex[2]; ci2 = exi[2]; }
            #pragma unroll
            for (int off = 4; off >= 1; off >>= 1) {
                const float ov = __shfl_xor(cb, off, 8);
                const int   oi = __shfl_xor(ci2, off, 8);
                if (ov > cb || (ov == cb && oi < ci2)) { cb = ov; ci2 = oi; }
            }
            if (k == 0) m0 = cb;
            const float e = __expf(cb - m0);
            den += e;
            #pragma unroll
            for (int s2 = 0; s2 < 3; ++s2)
                if (exi[s2] == ci2) ex[s2] = -3.0e38f;   // indices distinct -> safe pop
            if ((k & 7) == cg) {
                if (k < 8) { wkA2 = e; ikx = ci2; }
                else       { wkB2 = e; iky = ci2; }
            }
        }

        const float invden = 1.0f / den;
        float4 oA = make_float4(0.f, 0.f, 0.f, 0.f);
        float4 oB = make_float4(0.f, 0.f, 0.f, 0.f);
        #pragma unroll 1
        for (int k = 0; k < 16; ++k) {
            const bool hi = k >= 8;
            const float wsrc = hi ? wkB2 : wkA2;
            const int   isrc = hi ? iky : ikx;
            const float wv = __shfl(wsrc, k & 7, 8);
            const int   iv = __shfl(isrc, k & 7, 8);
            const float* vp = Vb + (size_t)iv*DD + (cg << 3);
            const float4 va  = *(const float4*)vp;
            const float4 vb2 = *(const float4*)(vp + 4);
            oA.x = fmaf(wv, va.x, oA.x);  oA.y = fmaf(wv, va.y, oA.y);
            oA.z = fmaf(wv, va.z, oA.z);  oA.w = fmaf(wv, va.w, oA.w);
            oB.x = fmaf(wv, vb2.x, oB.x); oB.y = fmaf(wv, vb2.y, oB.y);
            oB.z = fmaf(wv, vb2.z, oB.z); oB.w = fmaf(wv, vb2.w, oB.w);
        }
        oA.x *= invden; oA.y *= invden; oA.z *= invden; oA.w *= invden;
        oB.x *= invden; oB.y *= invden; oB.z *= invden; oB.w *= invden;
        const size_t ob = (((size_t)s*NN + n0 + r0 + rr)*BH + b)*DD + (cg << 3);
        *(float4*)&out[ob]     = oA;
        *(float4*)&out[ob + 4] = oB;

        // exact novelty
        float ns = xn;
        #pragma unroll
        for (int off = 4; off >= 1; off >>= 1)
            ns = fmaxf(ns, __shfl_xor(ns, off, 8));
        if (cg == 0) {
            const int nidx = ((s*NN + n0 + r0 + rr)*BH) + b;
            const float w = wnov[nidx], su = surprise[nidx];
            ws[WS_NOV + sb*NN + n0 + r0 + rr] =
                w*su + (1.f - w)*(1.f - fmaxf(ns, 0.f));
        }
    }
}

// ---------------------------------------------------------------------------
// Kernel 2: per (s,b) top-64 of novelty over N=1024 + cand_weight.
// Single-wave tournament (no barriers).
// ---------------------------------------------------------------------------
__global__ __launch_bounds__(64)
void k2_topc(float* __restrict__ ws)
{
    const int sb = blockIdx.x;
    const int lane = threadIdx.x;          // 0..63
    float av[16]; int ai[16];
    const int base = WS_NOV + sb*NN + lane*16;
    #pragma unroll
    for (int j = 0; j < 16; ++j) { av[j] = ws[base + j]; ai[j] = lane*16 + j; }

    #pragma unroll
    for (int pass = 0; pass < 16; ++pass) {
        #pragma unroll
        for (int i = (pass & 1); i + 1 < 16; i += 2) {
            const bool sw = (av[i] < av[i+1]) ||
                            (av[i] == av[i+1] && ai[i] > ai[i+1]);
            const float t0 = sw ? av[i+1] : av[i];
            const float t1 = sw ? av[i]   : av[i+1];
            av[i] = t0; av[i+1] = t1;
            const int u0 = sw ? ai[i+1] : ai[i];
            const int u1 = sw ? ai[i]   : ai[i+1];
            ai[i] = u0; ai[i+1] = u1;
        }
    }

    float kv = 0.f; int ki = 0;
    #pragma unroll 1
    for (int k = 0; k < CC; ++k) {
        float lv2 = av[0]; int key = lane;
        #pragma unroll
        for (int off = 32; off >= 1; off >>= 1) {
            const float ov = __shfl_xor(lv2, off, 64);
            const int   ok = __shfl_xor(key, off, 64);
            if (ov > lv2 || (ov == lv2 && ok < key)) { lv2 = ov; key = ok; }
        }
        const int widx = __shfl(ai[0], key, 64);
        if (lane == k) { kv = lv2; ki = widx; }
        if (lane == key) {
            #pragma unroll
            for (int i = 0; i < 15; ++i) { av[i] = av[i+1]; ai[i] = ai[i+1]; }
            av[15] = -3.0e38f;
        }
    }

    float sum = kv;
    #pragma unroll
    for (int off = 32; off >= 1; off >>= 1) sum += __shfl_xor(sum, off, 64);
    ((int*)ws)[WS_CI + sb*CC + lane] = ki;
    ws[WS_CW + sb*CC + lane] = kv / (sum + EPSV);
}

// ---------------------------------------------------------------------------
// Kernel 3a: gather cand_K/cand_V, unit-normalize cand_K
// ---------------------------------------------------------------------------
__global__ __launch_bounds__(256)
void k3a_gather(const float* __restrict__ qn, const float* __restrict__ vn,
                float* __restrict__ ws)
{
    const int sb = blockIdx.x; const int s = sb >> 3, b = sb & 7;
    const int t = threadIdx.x;
    const int cc = t >> 2, qd = t & 3;
    const int idx = ((const int*)ws)[WS_CI + sb*CC + cc];
    const size_t base = (((size_t)s*NN + idx)*BH + b)*DD + qd*16;

    float4 a[4]; float ss = 0.f;
    #pragma unroll
    for (int k = 0; k < 4; ++k) {
        a[k] = *(const float4*)&qn[base + (k << 2)];
        ss = fmaf(a[k].x, a[k].x, ss); ss = fmaf(a[k].y, a[k].y, ss);
        ss = fmaf(a[k].z, a[k].z, ss); ss = fmaf(a[k].w, a[k].w, ss);
    }
    #pragma unroll
    for (int off = 2; off >= 1; off >>= 1) ss += __shfl_xor(ss, off, 4);
    const float sc = 1.0f / fmaxf(sqrtf(ss), EPSV);

    float* ck = ws + WS_CKN + ((size_t)sb*CC + cc)*DD + qd*16;
    float* cv = ws + WS_CV  + ((size_t)sb*CC + cc)*DD + qd*16;
    #pragma unroll
    for (int k = 0; k < 4; ++k) {
        float4 o = a[k]; o.x *= sc; o.y *= sc; o.z *= sc; o.w *= sc;
        *(float4*)&ck[k << 2] = o;
        *(float4*)&cv[k << 2] = *(const float4*)&vn[base + (k << 2)];
    }
}

// ---------------------------------------------------------------------------
// Kernel 3b: slot-softmax partial stats.
// ---------------------------------------------------------------------------
__global__ __launch_bounds__(256)
void k3b_stats(const float* __restrict__ emK, const float* __restrict__ emS,
               const float* __restrict__ tau, const float* __restrict__ wwp,
               float* __restrict__ ws)
{
    const int sb = blockIdx.x;
    const int mc = blockIdx.y;           // m-chunk of 128
    const int t = threadIdx.x;
    const int rg = t >> 3, cg = t & 7;
    const int c0 = rg << 1;

    __shared__ float ckL[64][68];
    __shared__ float Kt[64][68];
    __shared__ float Sm[64];

    #pragma unroll
    for (int k = 0; k < 4; ++k) {
        const int fi = t + (k << 8);
        const int row = fi >> 4;
        const int col = (fi & 15) << 2;
        *(float4*)&ckL[row][col] =
            *(const float4*)&ws[WS_CKN + ((size_t)sb*CC + row)*DD + col];
    }

    const float invt = 1.0f / fmaxf(tau[sb], 0.01f);
    const float wwv = wwp[sb];
    const float* Kb = emK + (size_t)sb*MM*DD;
    const float* Sb = emS + (size_t)sb*MM;

    float rmax[2] = {-3.0e38f, -3.0e38f};
    float rsum[2] = {0.f, 0.f};

    #pragma unroll 1
    for (int tt = 0; tt < 2; ++tt) {
        const int mb = (mc << 7) + (tt << 6);
        __syncthreads();
        #pragma unroll
        for (int k = 0; k < 4; ++k) {
            const int fi = t + (k << 8);
            const int row = fi >> 4;
            const int col = (fi & 15) << 2;
            *(float4*)&Kt[row][col] = *(const float4*)&Kb[((size_t)(mb + row))*DD + col];
        }
        if (t < 64) Sm[t] = Sb[mb + t];
        __syncthreads();

        float acc[2][8];
        #pragma unroll
        for (int rr = 0; rr < 2; ++rr)
            #pragma unroll
            for (int j = 0; j < 8; ++j) acc[rr][j] = 0.f;

        #pragma unroll 4
        for (int ch = 0; ch < 16; ++ch) {
            const float4 ca = *(const float4*)&ckL[c0][ch << 2];
            const float4 cb = *(const float4*)&ckL[c0 + 1][ch << 2];
            #pragma unroll
            for (int j = 0; j < 8; ++j) {
                const float4 k4 = *(const float4*)&Kt[cg + (j << 3)][ch << 2];
                acc[0][j] = FMA4(ca, k4, acc[0][j]);
                acc[1][j] = FMA4(cb, k4, acc[1][j]);
            }
        }

        #pragma unroll
        for (int rr = 0; rr < 2; ++rr) {
            float z[8];
            #pragma unroll
            for (int j = 0; j < 8; ++j)
                z[j] = (acc[rr][j] - wwv*Sm[cg + (j << 3)]) * invt;
            float tmax = z[0];
            #pragma unroll
            for (int j = 1; j < 8; ++j) tmax = fmaxf(tmax, z[j]);
            #pragma unroll
            for (int off = 4; off >= 1; off >>= 1)
                tmax = fmaxf(tmax, __shfl_xor(tmax, off, 8));
            const float nm = fmaxf(rmax[rr], tmax);
            float ts = 0.f;
            #pragma unroll
            for (int j = 0; j < 8; ++j) ts += __expf(z[j] - nm);
            #pragma unroll
            for (int off = 4; off >= 1; off >>= 1) ts += __shfl_xor(ts, off, 8);
            rsum[rr] = rsum[rr]*__expf(rmax[rr] - nm) + ts;
            rmax[rr] = nm;
        }
    }
    if (cg == 0) {
        #pragma unroll
        for (int rr = 0; rr < 2; ++rr) {
            ws[WS_PMAX + ((size_t)sb*CC + c0 + rr)*16 + mc] = rmax[rr];
            ws[WS_PSUM + ((size_t)sb*CC + c0 + rr)*16 + mc] = rsum[rr];
        }
    }
}

// ---------------------------------------------------------------------------
// Kernel 3c: per (s,b, 64-m tile): alpha, alpha_per_slot, blends, updates
// ---------------------------------------------------------------------------
__global__ __launch_bounds__(256)
void k3c_write(const float* __restrict__ emK, const float* __restrict__ emV,
               const float* __restrict__ emS, const float* __restrict__ emA,
               const float* __restrict__ gem, const float* __restrict__ tau,
               const float* __restrict__ dec, const float* __restrict__ wwp,
             float* __restrict__ outK, float* __restrict__ outV,
             float* __restrict__ outS, float* __restrict__ outA,
             float* __restrict__ ws)
{
    const int sb = blockIdx.x; const int m0 = blockIdx.y << 6;
    const int t = threadIdx.x;
    __shared__ float ckn[64][68];
    __shared__ float cvv[64][68];
    __shared__ float alphaT[64][64];   // [c][m]
    __shared__ float apsL[64];
    __shared__ float psum[4][64];
    __shared__ float pn[4][64];
    __shared__ float mx[64], gs[64], Sl[64];

    const float gv  = gem[sb];
    const float invt = 1.0f / fmaxf(tau[sb], 0.01f);
    const float wwv = wwp[sb];
    const float dcv = dec[sb];

    #pragma unroll
    for (int k = 0; k < 4; ++k) {
        const int fid = t + (k << 8);
        const int row = fid >> 4;
        const int col = (fid & 15) << 2;
        *(float4*)&ckn[row][col] = *(const float4*)&ws[WS_CKN + ((size_t)sb*CC + row)*DD + col];
        *(float4*)&cvv[row][col] = *(const float4*)&ws[WS_CV  + ((size_t)sb*CC + row)*DD + col];
    }
    if (t < 64) {
        float mg = -3.0e38f;
        #pragma unroll
        for (int p = 0; p < 16; ++p)
            mg = fmaxf(mg, ws[WS_PMAX + ((size_t)sb*CC + t)*16 + p]);
        float sg = 0.f;
        #pragma unroll
        for (int p = 0; p < 16; ++p)
            sg += ws[WS_PSUM + ((size_t)sb*CC + t)*16 + p] *
                  __expf(ws[WS_PMAX + ((size_t)sb*CC + t)*16 + p] - mg);
        const float cw = ws[WS_CW + sb*CC + t];
        mx[t] = mg;
        gs[t] = gv * cw / sg;
        Sl[t] = emS[(size_t)sb*MM + m0 + t];
    }
    __syncthreads();

    const int m = t & 63, w = t >> 6;

    {
        float acc[16];
        #pragma unroll
        for (int i = 0; i < 16; ++i) acc[i] = 0.f;
        const float* Krow = emK + ((size_t)sb*MM + m0 + m)*DD;
        #pragma unroll 4
        for (int ch = 0; ch < 16; ++ch) {
            const float4 k4 = *(const float4*)&Krow[ch << 2];
            #pragma unroll
            for (int i = 0; i < 16; ++i) {
                const float4 c4 = *(const float4*)&ckn[(w << 4) + i][ch << 2];
                acc[i] = FMA4(k4, c4, acc[i]);
            }
        }
        const float Sv = Sl[m];
        #pragma unroll
        for (int i = 0; i < 16; ++i) {
            const int c = (w << 4) + i;
            const float zz = (acc[i] - wwv*Sv) * invt;
            alphaT[c][m] = gs[c] * __expf(zz - mx[c]);
        }
    }
    __syncthreads();

    {
        float p = 0.f;
        #pragma unroll
        for (int i = 0; i < 16; ++i) p += alphaT[(w << 4) + i][m];
        psum[w][m] = p;
    }
    __syncthreads();
    if (t < 64) apsL[t] = (psum[0][t] + psum[1][t]) + (psum[2][t] + psum[3][t]);
    __syncthreads();

    float bk[16], bv[16];
    #pragma unroll
    for (int i = 0; i < 16; ++i) { bk[i] = 0.f; bv[i] = 0.f; }
    for (int cI = 0; cI < 64; ++cI) {
        const float a = alphaT[cI][m];
        #pragma unroll
        for (int k = 0; k < 4; ++k) {
            const float4 c4 = *(const float4*)&ckn[cI][(w << 4) + (k << 2)];
            const float4 v4 = *(const float4*)&cvv[cI][(w << 4) + (k << 2)];
            bk[(k<<2)+0] = fmaf(a, c4.x, bk[(k<<2)+0]);
            bk[(k<<2)+1] = fmaf(a, c4.y, bk[(k<<2)+1]);
            bk[(k<<2)+2] = fmaf(a, c4.z, bk[(k<<2)+2]);
            bk[(k<<2)+3] = fmaf(a, c4.w, bk[(k<<2)+3]);
            bv[(k<<2)+0] = fmaf(a, v4.x, bv[(k<<2)+0]);
            bv[(k<<2)+1] = fmaf(a, v4.y, bv[(k<<2)+1]);
            bv[(k<<2)+2] = fmaf(a, v4.z, bv[(k<<2)+2]);
            bv[(k<<2)+3] = fmaf(a, v4.w, bv[(k<<2)+3]);
        }
    }

    const float aps = apsL[m];
    const float idn = 1.0f / fmaxf(aps, EPSV);
    float ssq = 0.f;
    #pragma unroll
    for (int i = 0; i < 16; ++i) { bk[i] *= idn; bv[i] *= idn; ssq = fmaf(bk[i], bk[i], ssq); }
    pn[w][m] = ssq;
    __syncthreads();
    const float nrm2 = (pn[0][m] + pn[1][m]) + (pn[2][m] + pn[3][m]);
    const float innv = 1.0f / fmaxf(sqrtf(nrm2), EPSV);
    const float ae = fminf(aps, 1.0f);
    const float oma = 1.0f - ae;
    const bool upd = aps > EPSV;
    const size_t gb = ((size_t)sb*MM + m0 + m)*DD + (w << 4);
    #pragma unroll
    for (int kq = 0; kq < 4; ++kq) {
        const float4 kk = *(const float4*)&emK[gb + (kq << 2)];
        const float4 vv = *(const float4*)&emV[gb + (kq << 2)];
        float4 nk, nv2;
        if (upd) {
            nk.x = oma*kk.x + ae*(bk[(kq<<2)+0]*innv);
            nk.y = oma*kk.y + ae*(bk[(kq<<2)+1]*innv);
            nk.z = oma*kk.z + ae*(bk[(kq<<2)+2]*innv);
            nk.w = oma*kk.w + ae*(bk[(kq<<2)+3]*innv);
            nv2.x = oma*vv.x + ae*bv[(kq<<2)+0];
            nv2.y = oma*vv.y + ae*bv[(kq<<2)+1];
            nv2.z = oma*vv.z + ae*bv[(kq<<2)+2];
            nv2.w = oma*vv.w + ae*bv[(kq<<2)+3];
        } else { nk = kk; nv2 = vv; }
        *(float4*)&outK[gb + (kq << 2)] = nk;
        *(float4*)&outV[gb + (kq << 2)] = nv2;
    }
    if (w == 0) {
        const float pre = fminf(fmaxf(Sl[m] + aps, 0.f), SMAXV) * dcv;
        outS[(size_t)sb*MM + m0 + m] = pre;
        outA[(size_t)sb*MM + m0 + m] = emA[(size_t)sb*MM + m0 + m] * (1.0f - aps);
        float tot = pre;
        #pragma unroll
        for (int off = 32; off >= 1; off >>= 1) tot += __shfl_xor(tot, off, 64);
        if (m == 0) atomicAdd(&ws[WS_TOTS + sb], tot);
    }
}

// ---------------------------------------------------------------------------
// Kernel 4: budget rescale of new_S
// ---------------------------------------------------------------------------
__global__ __launch_bounds__(256)
void k4_budget(float* __restrict__ outS, const float* __restrict__ ws)
{
    const int sb = blockIdx.x;
    const float sc = fminf(1.0f, BUDGETV / (ws[WS_TOTS + sb] + EPSV));
    for (int m = threadIdx.x; m < MM; m += 256)
        outS[(size_t)sb*MM + m] *= sc;
}

extern "C" void kernel_launch(void* const* d_in, const int* in_sizes, int n_in,
                              void* d_out, int out_size, void* d_ws, size_t ws_size,
                              hipStream_t stream)
{
    const float* q   = (const float*)d_in[0];
    const float* qnv = (const float*)d_in[1];
    const float* vnv = (const float*)d_in[2];
    const float* sur = (const float*)d_in[3];
    const float* wn  = (const float*)d_in[4];
    const float* gem = (const float*)d_in[5];
    const float* tau = (const float*)d_in[6];
    const float* dec = (const float*)d_in[7];
    const float* wwp = (const float*)d_in[8];
    const float* emK = (const float*)d_in[9];
    const float* emV = (const float*)d_in[10];
    const float* emS = (const float*)d_in[11];
    const float* emA = (const float*)d_in[12];

    float* out  = (float*)d_out;
    float* outK = out + 2097152;
    float* outV = out + 6291456;
    float* outS = out + 10485760;
    float* outA = out + 10551296;
    float* ws = (float*)d_ws;

    // f16 copy of emK lives in the outV output region (k3c rewrites it later)
    unsigned short* Kh = (unsigned short*)outV;

    hipMemsetAsync((char*)d_ws + WS_TOTS*sizeof(float), 0, 32*sizeof(float), stream);

    k0_cvt<<<2048, 256, 0, stream>>>(emK, Kh);
    k1_read<<<dim3(32, 16), 256, 0, stream>>>(q, qnv, sur, wn, emK, Kh, emV, emS, out, ws);
    k2_topc<<<32, 64, 0, stream>>>(ws);
    k3a_gather<<<32, 256, 0, stream>>>(qnv, vnv, ws);
    k3b_stats<<<dim3(32, 16), 256, 0, stream>>>(emK, emS, tau, wwp, ws);
    k3c_write<<<dim3(32, 32), 256, 0, stream>>>(emK, emV, emS, emA, gem, tau, dec, wwp,
                                                outK, outV, outS, outA, ws);
    k4_budget<<<32, 256, 0, stream>>>(outS, ws);
}

// Round 8
// 2784.554 us; speedup vs baseline: 1.0496x; 1.0496x over previous
//
#include <hip/hip_runtime.h>
#include <math.h>

#define BSZ 4
#define NN 1024
#define BH 8
#define DD 64
#define MM 2048
#define KRET 16
#define CC 64
#define NEGV -1000000000.0f
#define EPSV 1e-8f
#define SMAXV 4.0f
#define BUDGETV 512.0f

#define FMA4(a4, b4, acc) \
    fmaf((a4).w, (b4).w, fmaf((a4).z, (b4).z, fmaf((a4).y, (b4).y, fmaf((a4).x, (b4).x, (acc)))))

// ws layout (float-element offsets)
#define WS_NOV  0         // [32][1024] novelty
#define WS_CI   32768     // int [32][64] candidate indices
#define WS_CW   34816     // [32][64] cand_weight
#define WS_CKN  36864     // [32][64][64] unit-normalized cand_K
#define WS_CV   167936    // [32][64][64] cand_V
#define WS_PMAX 299008    // [32][64][16] slot-softmax partial max
#define WS_PSUM 331776    // [32][64][16] slot-softmax partial sumexp
#define WS_TOTS 364544    // [32] new_S totals (memset to 0 each call)

typedef _Float16 h2v __attribute__((ext_vector_type(2)));

__device__ __forceinline__ float dot8h(const uint4 a, const uint4 b, float c)
{
#if __has_builtin(__builtin_amdgcn_fdot2)
    c = __builtin_amdgcn_fdot2(__builtin_bit_cast(h2v, a.x), __builtin_bit_cast(h2v, b.x), c, false);
    c = __builtin_amdgcn_fdot2(__builtin_bit_cast(h2v, a.y), __builtin_bit_cast(h2v, b.y), c, false);
    c = __builtin_amdgcn_fdot2(__builtin_bit_cast(h2v, a.z), __builtin_bit_cast(h2v, b.z), c, false);
    c = __builtin_amdgcn_fdot2(__builtin_bit_cast(h2v, a.w), __builtin_bit_cast(h2v, b.w), c, false);
#else
    const h2v ax = __builtin_bit_cast(h2v, a.x), bx = __builtin_bit_cast(h2v, b.x);
    const h2v ay = __builtin_bit_cast(h2v, a.y), by = __builtin_bit_cast(h2v, b.y);
    const h2v az = __builtin_bit_cast(h2v, a.z), bz = __builtin_bit_cast(h2v, b.z);
    const h2v aw = __builtin_bit_cast(h2v, a.w), bw = __builtin_bit_cast(h2v, b.w);
    c = fmaf((float)ax[0], (float)bx[0], c); c = fmaf((float)ax[1], (float)bx[1], c);
    c = fmaf((float)ay[0], (float)by[0], c); c = fmaf((float)ay[1], (float)by[1], c);
    c = fmaf((float)az[0], (float)bz[0], c); c = fmaf((float)az[1], (float)bz[1], c);
    c = fmaf((float)aw[0], (float)bw[0], c); c = fmaf((float)aw[1], (float)bw[1], c);
#endif
    return c;
}

__device__ __forceinline__ unsigned pk2h(float a, float b)
{
#if __has_builtin(__builtin_amdgcn_cvt_pkrtz)
    return __builtin_bit_cast(unsigned, __builtin_amdgcn_cvt_pkrtz(a, b));
#else
    const unsigned short ua = __builtin_bit_cast(unsigned short, (_Float16)a);
    const unsigned short ub = __builtin_bit_cast(unsigned short, (_Float16)b);
    return (unsigned)ua | ((unsigned)ub << 16);
#endif
}

// ---------------------------------------------------------------------------
// Kernel 0: convert emK (f32) -> f16 into scratch (outV region; k3c rewrites
// outV later). 4M elements, 8 per thread.
// ---------------------------------------------------------------------------
__global__ __launch_bounds__(256)
void k0_cvt(const float* __restrict__ emK, unsigned short* __restrict__ Kh)
{
    const size_t base = ((size_t)blockIdx.x*256 + threadIdx.x)*8;
    const float4 a = *(const float4*)&emK[base];
    const float4 b = *(const float4*)&emK[base + 4];
    uint4 o;
    o.x = pk2h(a.x, a.y); o.y = pk2h(a.z, a.w);
    o.z = pk2h(b.x, b.y); o.w = pk2h(b.z, b.w);
    *(uint4*)&Kh[base] = o;
}

// ---------------------------------------------------------------------------
// Kernel 1 (R10): f16 SCREEN + f32 RESCORE.
// R7's 2733us regression was rule-#20 scratch spill: the epilogue's
// `#pragma unroll 1` over rr made lv/li/nv/ni runtime-indexed -> local
// memory for the whole kernel (FETCH 4.8GB, VALUBusy 8%). Fix: full unroll
// on rr (compile-time indexing everywhere). Screen math unchanged from R7
// (passed, absmax 0.0019): v_dot2_f32_f16 dots, f16 LDS tiles, exact f32
// rescore of approx top-24 + top-4-novelty per lane.
// ---------------------------------------------------------------------------
__global__ __launch_bounds__(256, 2)
void k1_read(const float* __restrict__ q, const float* __restrict__ qn,
             const float* __restrict__ surprise, const float* __restrict__ wnov,
             const float* __restrict__ emK, const unsigned short* __restrict__ Kh,
             const float* __restrict__ emV, const float* __restrict__ emS,
             float* __restrict__ out, float* __restrict__ ws)
{
    const int sb = blockIdx.x;            // 0..31  (s*8+b)
    const int s = sb >> 3, b = sb & 7;
    const int n0 = blockIdx.y << 6;       // n-tile of 64
    const int t = threadIdx.x;
    const int rg = t >> 3;                // row-group 0..31
    const int cg = t & 7;                 // col sub-lane 0..7
    const int r0 = rg << 1;               // this thread's 2 rows

    __shared__ unsigned short qh [64][72];   // f16, row stride 144B (16B-aligned, +4 banks/row)
    __shared__ unsigned short qnh[64][72];
    __shared__ unsigned short Kth[64][72];
    __shared__ float Sm[64];

    // stage q / q_nov tile as f16 (on-the-fly convert)
    #pragma unroll
    for (int k = 0; k < 4; ++k) {
        const int fi = t + (k << 8);
        const int row = fi >> 4;
        const int col = (fi & 15) << 2;
        const size_t qb = (((size_t)s*NN + n0 + row)*BH + b)*DD + col;
        const float4 v  = *(const float4*)&q[qb];
        const float4 w4 = *(const float4*)&qn[qb];
        *(uint2*)&qh [row][col] = make_uint2(pk2h(v.x,  v.y),  pk2h(v.z,  v.w));
        *(uint2*)&qnh[row][col] = make_uint2(pk2h(w4.x, w4.y), pk2h(w4.z, w4.w));
    }

    // per-lane sorted-desc approx top-16 score lists + top-4 novelty trackers
    float lv[2][16]; int li[2][16];
    float nv[2][4];  int ni[2][4];
    #pragma unroll
    for (int rr = 0; rr < 2; ++rr) {
        #pragma unroll
        for (int i = 0; i < 16; ++i) { lv[rr][i] = -3.0e38f; li[rr][i] = 0; }
        #pragma unroll
        for (int i = 0; i < 4; ++i)  { nv[rr][i] = -3.0e38f; ni[rr][i] = 0; }
    }

    const unsigned short* Khb = Kh + (size_t)sb*MM*DD;
    const float* Sb = emS + (size_t)sb*MM;

#define CEB(x, y) { const bool sw_ = bv[y] > bv[x];                       \
    const float f0_ = sw_ ? bv[y] : bv[x]; const float f1_ = sw_ ? bv[x] : bv[y]; \
    bv[x] = f0_; bv[y] = f1_;                                             \
    const int i0_ = sw_ ? bi[y] : bi[x]; const int i1_ = sw_ ? bi[x] : bi[y]; \
    bi[x] = i0_; bi[y] = i1_; }
#define CEL(x, y) { const bool sw_ = lv[rr][y] > lv[rr][x];               \
    const float f0_ = sw_ ? lv[rr][y] : lv[rr][x];                        \
    const float f1_ = sw_ ? lv[rr][x] : lv[rr][y];                        \
    lv[rr][x] = f0_; lv[rr][y] = f1_;                                     \
    const int i0_ = sw_ ? li[rr][y] : li[rr][x];                          \
    const int i1_ = sw_ ? li[rr][x] : li[rr][y];                          \
    li[rr][x] = i0_; li[rr][y] = i1_; }

    #pragma unroll 1
    for (int mt = 0; mt < MM/64; ++mt) {
        __syncthreads();
        #pragma unroll
        for (int k = 0; k < 2; ++k) {
            const int fi = t + (k << 8);
            const int row = fi >> 3;
            const int col8 = (fi & 7) << 3;
            *(uint4*)&Kth[row][col8] =
                *(const uint4*)&Khb[((size_t)(mt*64 + row))*DD + col8];
        }
        if (t < 64) Sm[t] = Sb[mt*64 + t];
        __syncthreads();

        float acc[2][8], accn[2][8];
        #pragma unroll
        for (int rr = 0; rr < 2; ++rr)
            #pragma unroll
            for (int j = 0; j < 8; ++j) { acc[rr][j] = 0.f; accn[rr][j] = 0.f; }

        #pragma unroll
        for (int ch = 0; ch < 8; ++ch) {
            const uint4 qa  = *(const uint4*)&qh [r0][ch << 3];
            const uint4 na  = *(const uint4*)&qnh[r0][ch << 3];
            const uint4 qb4 = *(const uint4*)&qh [r0 + 1][ch << 3];
            const uint4 nb4 = *(const uint4*)&qnh[r0 + 1][ch << 3];
            #pragma unroll
            for (int j = 0; j < 8; ++j) {
                const uint4 k8 = *(const uint4*)&Kth[cg + (j << 3)][ch << 3];
                acc[0][j]  = dot8h(qa,  k8, acc[0][j]);
                accn[0][j] = dot8h(na,  k8, accn[0][j]);
                acc[1][j]  = dot8h(qb4, k8, acc[1][j]);
                accn[1][j] = dot8h(nb4, k8, accn[1][j]);
            }
        }

        float sq[2][8], sn[2][8];
        #pragma unroll
        for (int j = 0; j < 8; ++j) {
            const int ml = cg + (j << 3);
            const bool act = Sm[ml] > 0.f;
            sq[0][j] = act ? acc[0][j] : NEGV;
            sq[1][j] = act ? acc[1][j] : NEGV;
            sn[0][j] = act ? accn[0][j] : -1.0f;
            sn[1][j] = act ? accn[1][j] : -1.0f;
        }

        #pragma unroll
        for (int rr = 0; rr < 2; ++rr) {
            // novelty: tile-best -> sorted-4 tracker
            float bn = sn[rr][0]; int bji = 0;
            #pragma unroll
            for (int j = 1; j < 8; ++j)
                if (sn[rr][j] > bn) { bn = sn[rr][j]; bji = j; }
            if (bn > nv[rr][3]) {
                const int bgi = mt*64 + cg + (bji << 3);
                if (bn > nv[rr][1]) {
                    nv[rr][3] = nv[rr][2]; ni[rr][3] = ni[rr][2];
                    nv[rr][2] = nv[rr][1]; ni[rr][2] = ni[rr][1];
                    if (bn > nv[rr][0]) {
                        nv[rr][1] = nv[rr][0]; ni[rr][1] = ni[rr][0];
                        nv[rr][0] = bn; ni[rr][0] = bgi;
                    } else { nv[rr][1] = bn; ni[rr][1] = bgi; }
                } else if (bn > nv[rr][2]) {
                    nv[rr][3] = nv[rr][2]; ni[rr][3] = ni[rr][2];
                    nv[rr][2] = bn; ni[rr][2] = bgi;
                } else { nv[rr][3] = bn; ni[rr][3] = bgi; }
            }

            // score batch top-16 merge (proven network from R5/R6)
            float bmax = sq[rr][0];
            #pragma unroll
            for (int j = 1; j < 8; ++j) bmax = fmaxf(bmax, sq[rr][j]);
            if (bmax > lv[rr][15]) {
                float bv[8]; int bi[8];
                #pragma unroll
                for (int j = 0; j < 8; ++j) {
                    bv[j] = sq[rr][j];
                    bi[j] = mt*64 + cg + (j << 3);
                }
                CEB(0,1) CEB(2,3) CEB(4,5) CEB(6,7)
                CEB(0,2) CEB(1,3) CEB(4,6) CEB(5,7)
                CEB(1,2) CEB(5,6)
                CEB(0,4) CEB(1,5) CEB(2,6) CEB(3,7)
                CEB(2,4) CEB(3,5)
                CEB(1,2) CEB(3,4) CEB(5,6)
                #pragma unroll
                for (int i = 0; i < 8; ++i) {
                    const bool tk = bv[7-i] > lv[rr][8+i];
                    if (tk) { lv[rr][8+i] = bv[7-i]; li[rr][8+i] = bi[7-i]; }
                }
                CEL(8,12) CEL(9,13) CEL(10,14) CEL(11,15)
                CEL(8,10) CEL(9,11) CEL(12,14) CEL(13,15)
                CEL(8,9)  CEL(10,11) CEL(12,13) CEL(14,15)
                CEL(0,15) CEL(1,14) CEL(2,13) CEL(3,12)
                CEL(4,11) CEL(5,10) CEL(6,9)  CEL(7,8)
                CEL(0,4) CEL(1,5) CEL(2,6) CEL(3,7)
                CEL(0,2) CEL(1,3) CEL(4,6) CEL(5,7)
                CEL(0,1) CEL(2,3) CEL(4,5) CEL(6,7)
                CEL(8,12) CEL(9,13) CEL(10,14) CEL(11,15)
                CEL(8,10) CEL(9,11) CEL(12,14) CEL(13,15)
                CEL(8,9)  CEL(10,11) CEL(12,13) CEL(14,15)
            }
        }
    }
#undef CEB
#undef CEL

    const float* Vb = emV + (size_t)sb*MM*DD;
    const float* Kb = emK + (size_t)sb*MM*DD;

    #pragma unroll                       // rr MUST be compile-time (rule #20: R7 bug)
    for (int rr = 0; rr < 2; ++rr) {
        // ---- Phase A: approx global top-24 indices (3 per lane) ----
        int ikA = 0, ikB = 0, ikC = 0;
        #pragma unroll 1
        for (int k = 0; k < 24; ++k) {
            float cb = lv[rr][0]; int ci2 = li[rr][0]; int key = cg;
            #pragma unroll
            for (int off = 4; off >= 1; off >>= 1) {
                const float ov = __shfl_xor(cb, off, 8);
                const int   ok = __shfl_xor(key, off, 8);
                const int   oi = __shfl_xor(ci2, off, 8);
                if (ov > cb || (ov == cb && ok < key)) { cb = ov; key = ok; ci2 = oi; }
            }
            if (key == cg) {
                #pragma unroll
                for (int i = 0; i < 15; ++i) { lv[rr][i] = lv[rr][i+1]; li[rr][i] = li[rr][i+1]; }
                lv[rr][15] = -3.0e38f;   // prevent duplicate re-pop past list depth
            }
            if ((k & 7) == cg) {
                if (k < 8) ikA = ci2; else if (k < 16) ikB = ci2; else ikC = ci2;
            }
        }

        // ---- Phase B: exact f32 rescore (3 score + 4 novelty per lane) ----
        const float* qrow  = q  + (((size_t)s*NN + n0 + r0 + rr)*BH + b)*DD;
        const float* qnrow = qn + (((size_t)s*NN + n0 + r0 + rr)*BH + b)*DD;
        const float* kA = Kb + (size_t)ikA*DD;
        const float* kB = Kb + (size_t)ikB*DD;
        const float* kC = Kb + (size_t)ikC*DD;
        const float* p1 = Kb + (size_t)ni[rr][0]*DD;
        const float* p2 = Kb + (size_t)ni[rr][1]*DD;
        const float* p3 = Kb + (size_t)ni[rr][2]*DD;
        const float* p4 = Kb + (size_t)ni[rr][3]*DD;
        float eA = 0.f, eB = 0.f, eC = 0.f, f1 = 0.f, f2 = 0.f, f3 = 0.f, f4 = 0.f;
        #pragma unroll
        for (int c2 = 0; c2 < 16; ++c2) {
            const float4 qv  = *(const float4*)&qrow[c2 << 2];
            const float4 nqv = *(const float4*)&qnrow[c2 << 2];
            eA = FMA4(qv,  *(const float4*)&kA[c2 << 2], eA);
            eB = FMA4(qv,  *(const float4*)&kB[c2 << 2], eB);
            eC = FMA4(qv,  *(const float4*)&kC[c2 << 2], eC);
            f1 = FMA4(nqv, *(const float4*)&p1[c2 << 2], f1);
            f2 = FMA4(nqv, *(const float4*)&p2[c2 << 2], f2);
            f3 = FMA4(nqv, *(const float4*)&p3[c2 << 2], f3);
            f4 = FMA4(nqv, *(const float4*)&p4[c2 << 2], f4);
        }
        float ex[3]; int exi[3];
        ex[0] = (Sb[ikA] > 0.f) ? eA : NEGV;  exi[0] = ikA;
        ex[1] = (Sb[ikB] > 0.f) ? eB : NEGV;  exi[1] = ikB;
        ex[2] = (Sb[ikC] > 0.f) ? eC : NEGV;  exi[2] = ikC;
        const float xn = fmaxf(
            fmaxf((Sb[ni[rr][0]] > 0.f) ? f1 : -1.0f, (Sb[ni[rr][1]] > 0.f) ? f2 : -1.0f),
            fmaxf((Sb[ni[rr][2]] > 0.f) ? f3 : -1.0f, (Sb[ni[rr][3]] > 0.f) ? f4 : -1.0f));

        // ---- Phase C: exact top-16 of 24 + softmax + P.V ----
        float m0 = 0.f, den = 0.f, wkA2 = 0.f, wkB2 = 0.f;
        int ikx = 0, iky = 0;
        #pragma unroll 1
        for (int k = 0; k < 16; ++k) {
            float cb = ex[0]; int ci2 = exi[0];
            if (ex[1] > cb || (ex[1] == cb && exi[1] < ci2)) { cb = ex[1]; ci2 = exi[1]; }
            if (ex[2] > cb || (ex[2] == cb && exi[2] < ci2)) { cb = ex[2]; ci2 = exi[2]; }
            #pragma unroll
            for (int off = 4; off >= 1; off >>= 1) {
                const float ov = __shfl_xor(cb, off, 8);
                const int   oi = __shfl_xor(ci2, off, 8);
                if (ov > cb || (ov == cb && oi < ci2)) { cb = ov; ci2 = oi; }
            }
            if (k == 0) m0 = cb;
            const float e = __expf(cb - m0);
            den += e;
            #pragma unroll
            for (int s2 = 0; s2 < 3; ++s2)
                if (exi[s2] == ci2) ex[s2] = -3.0e38f;   // indices distinct -> safe pop
            if ((k & 7) == cg) {
                if (k < 8) { wkA2 = e; ikx = ci2; }
                else       { wkB2 = e; iky = ci2; }
            }
        }

        const float invden = 1.0f / den;
        float4 oA = make_float4(0.f, 0.f, 0.f, 0.f);
        float4 oB = make_float4(0.f, 0.f, 0.f, 0.f);
        #pragma unroll 1
        for (int k = 0; k < 16; ++k) {
            const bool hi = k >= 8;
            const float wsrc = hi ? wkB2 : wkA2;
            const int   isrc = hi ? iky : ikx;
            const float wv = __shfl(wsrc, k & 7, 8);
            const int   iv = __shfl(isrc, k & 7, 8);
            const float* vp = Vb + (size_t)iv*DD + (cg << 3);
            const float4 va  = *(const float4*)vp;
            const float4 vb2 = *(const float4*)(vp + 4);
            oA.x = fmaf(wv, va.x, oA.x);  oA.y = fmaf(wv, va.y, oA.y);
            oA.z = fmaf(wv, va.z, oA.z);  oA.w = fmaf(wv, va.w, oA.w);
            oB.x = fmaf(wv, vb2.x, oB.x); oB.y = fmaf(wv, vb2.y, oB.y);
            oB.z = fmaf(wv, vb2.z, oB.z); oB.w = fmaf(wv, vb2.w, oB.w);
        }
        oA.x *= invden; oA.y *= invden; oA.z *= invden; oA.w *= invden;
        oB.x *= invden; oB.y *= invden; oB.z *= invden; oB.w *= invden;
        const size_t ob = (((size_t)s*NN + n0 + r0 + rr)*BH + b)*DD + (cg << 3);
        *(float4*)&out[ob]     = oA;
        *(float4*)&out[ob + 4] = oB;

        // exact novelty
        float ns = xn;
        #pragma unroll
        for (int off = 4; off >= 1; off >>= 1)
            ns = fmaxf(ns, __shfl_xor(ns, off, 8));
        if (cg == 0) {
            const int nidx = ((s*NN + n0 + r0 + rr)*BH) + b;
            const float w = wnov[nidx], su = surprise[nidx];
            ws[WS_NOV + sb*NN + n0 + r0 + rr] =
                w*su + (1.f - w)*(1.f - fmaxf(ns, 0.f));
        }
    }
}

// ---------------------------------------------------------------------------
// Kernel 2: per (s,b) top-64 of novelty over N=1024 + cand_weight.
// Single-wave tournament (no barriers).
// ---------------------------------------------------------------------------
__global__ __launch_bounds__(64)
void k2_topc(float* __restrict__ ws)
{
    const int sb = blockIdx.x;
    const int lane = threadIdx.x;          // 0..63
    float av[16]; int ai[16];
    const int base = WS_NOV + sb*NN + lane*16;
    #pragma unroll
    for (int j = 0; j < 16; ++j) { av[j] = ws[base + j]; ai[j] = lane*16 + j; }

    #pragma unroll
    for (int pass = 0; pass < 16; ++pass) {
        #pragma unroll
        for (int i = (pass & 1); i + 1 < 16; i += 2) {
            const bool sw = (av[i] < av[i+1]) ||
                            (av[i] == av[i+1] && ai[i] > ai[i+1]);
            const float t0 = sw ? av[i+1] : av[i];
            const float t1 = sw ? av[i]   : av[i+1];
            av[i] = t0; av[i+1] = t1;
            const int u0 = sw ? ai[i+1] : ai[i];
            const int u1 = sw ? ai[i]   : ai[i+1];
            ai[i] = u0; ai[i+1] = u1;
        }
    }

    float kv = 0.f; int ki = 0;
    #pragma unroll 1
    for (int k = 0; k < CC; ++k) {
        float lv2 = av[0]; int key = lane;
        #pragma unroll
        for (int off = 32; off >= 1; off >>= 1) {
            const float ov = __shfl_xor(lv2, off, 64);
            const int   ok = __shfl_xor(key, off, 64);
            if (ov > lv2 || (ov == lv2 && ok < key)) { lv2 = ov; key = ok; }
        }
        const int widx = __shfl(ai[0], key, 64);
        if (lane == k) { kv = lv2; ki = widx; }
        if (lane == key) {
            #pragma unroll
            for (int i = 0; i < 15; ++i) { av[i] = av[i+1]; ai[i] = ai[i+1]; }
            av[15] = -3.0e38f;
        }
    }

    float sum = kv;
    #pragma unroll
    for (int off = 32; off >= 1; off >>= 1) sum += __shfl_xor(sum, off, 64);
    ((int*)ws)[WS_CI + sb*CC + lane] = ki;
    ws[WS_CW + sb*CC + lane] = kv / (sum + EPSV);
}

// ---------------------------------------------------------------------------
// Kernel 3a: gather cand_K/cand_V, unit-normalize cand_K
// ---------------------------------------------------------------------------
__global__ __launch_bounds__(256)
void k3a_gather(const float* __restrict__ qn, const float* __restrict__ vn,
                float* __restrict__ ws)
{
    const int sb = blockIdx.x; const int s = sb >> 3, b = sb & 7;
    const int t = threadIdx.x;
    const int cc = t >> 2, qd = t & 3;
    const int idx = ((const int*)ws)[WS_CI + sb*CC + cc];
    const size_t base = (((size_t)s*NN + idx)*BH + b)*DD + qd*16;

    float4 a[4]; float ss = 0.f;
    #pragma unroll
    for (int k = 0; k < 4; ++k) {
        a[k] = *(const float4*)&qn[base + (k << 2)];
        ss = fmaf(a[k].x, a[k].x, ss); ss = fmaf(a[k].y, a[k].y, ss);
        ss = fmaf(a[k].z, a[k].z, ss); ss = fmaf(a[k].w, a[k].w, ss);
    }
    #pragma unroll
    for (int off = 2; off >= 1; off >>= 1) ss += __shfl_xor(ss, off, 4);
    const float sc = 1.0f / fmaxf(sqrtf(ss), EPSV);

    float* ck = ws + WS_CKN + ((size_t)sb*CC + cc)*DD + qd*16;
    float* cv = ws + WS_CV  + ((size_t)sb*CC + cc)*DD + qd*16;
    #pragma unroll
    for (int k = 0; k < 4; ++k) {
        float4 o = a[k]; o.x *= sc; o.y *= sc; o.z *= sc; o.w *= sc;
        *(float4*)&ck[k << 2] = o;
        *(float4*)&cv[k << 2] = *(const float4*)&vn[base + (k << 2)];
    }
}

// ---------------------------------------------------------------------------
// Kernel 3b: slot-softmax partial stats.
// ---------------------------------------------------------------------------
__global__ __launch_bounds__(256)
void k3b_stats(const float* __restrict__ emK, const float* __restrict__ emS,
               const float* __restrict__ tau, const float* __restrict__ wwp,
               float* __restrict__ ws)
{
    const int sb = blockIdx.x;
    const int mc = blockIdx.y;           // m-chunk of 128
    const int t = threadIdx.x;
    const int rg = t >> 3, cg = t & 7;
    const int c0 = rg << 1;

    __shared__ float ckL[64][68];
    __shared__ float Kt[64][68];
    __shared__ float Sm[64];

    #pragma unroll
    for (int k = 0; k < 4; ++k) {
        const int fi = t + (k << 8);
        const int row = fi >> 4;
        const int col = (fi & 15) << 2;
        *(float4*)&ckL[row][col] =
            *(const float4*)&ws[WS_CKN + ((size_t)sb*CC + row)*DD + col];
    }

    const float invt = 1.0f / fmaxf(tau[sb], 0.01f);
    const float wwv = wwp[sb];
    const float* Kb = emK + (size_t)sb*MM*DD;
    const float* Sb = emS + (size_t)sb*MM;

    float rmax[2] = {-3.0e38f, -3.0e38f};
    float rsum[2] = {0.f, 0.f};

    #pragma unroll 1
    for (int tt = 0; tt < 2; ++tt) {
        const int mb = (mc << 7) + (tt << 6);
        __syncthreads();
        #pragma unroll
        for (int k = 0; k < 4; ++k) {
            const int fi = t + (k << 8);
            const int row = fi >> 4;
            const int col = (fi & 15) << 2;
            *(float4*)&Kt[row][col] = *(const float4*)&Kb[((size_t)(mb + row))*DD + col];
        }
        if (t < 64) Sm[t] = Sb[mb + t];
        __syncthreads();

        float acc[2][8];
        #pragma unroll
        for (int rr = 0; rr < 2; ++rr)
            #pragma unroll
            for (int j = 0; j < 8; ++j) acc[rr][j] = 0.f;

        #pragma unroll 4
        for (int ch = 0; ch < 16; ++ch) {
            const float4 ca = *(const float4*)&ckL[c0][ch << 2];
            const float4 cb = *(const float4*)&ckL[c0 + 1][ch << 2];
            #pragma unroll
            for (int j = 0; j < 8; ++j) {
                const float4 k4 = *(const float4*)&Kt[cg + (j << 3)][ch << 2];
                acc[0][j] = FMA4(ca, k4, acc[0][j]);
                acc[1][j] = FMA4(cb, k4, acc[1][j]);
            }
        }

        #pragma unroll
        for (int rr = 0; rr < 2; ++rr) {
            float z[8];
            #pragma unroll
            for (int j = 0; j < 8; ++j)
                z[j] = (acc[rr][j] - wwv*Sm[cg + (j << 3)]) * invt;
            float tmax = z[0];
            #pragma unroll
            for (int j = 1; j < 8; ++j) tmax = fmaxf(tmax, z[j]);
            #pragma unroll
            for (int off = 4; off >= 1; off >>= 1)
                tmax = fmaxf(tmax, __shfl_xor(tmax, off, 8));
            const float nm = fmaxf(rmax[rr], tmax);
            float ts = 0.f;
            #pragma unroll
            for (int j = 0; j < 8; ++j) ts += __expf(z[j] - nm);
            #pragma unroll
            for (int off = 4; off >= 1; off >>= 1) ts += __shfl_xor(ts, off, 8);
            rsum[rr] = rsum[rr]*__expf(rmax[rr] - nm) + ts;
            rmax[rr] = nm;
        }
    }
    if (cg == 0) {
        #pragma unroll
        for (int rr = 0; rr < 2; ++rr) {
            ws[WS_PMAX + ((size_t)sb*CC + c0 + rr)*16 + mc] = rmax[rr];
            ws[WS_PSUM + ((size_t)sb*CC + c0 + rr)*16 + mc] = rsum[rr];
        }
    }
}

// ---------------------------------------------------------------------------
// Kernel 3c: per (s,b, 64-m tile): alpha, alpha_per_slot, blends, updates
// ---------------------------------------------------------------------------
__global__ __launch_bounds__(256)
void k3c_write(const float* __restrict__ emK, const float* __restrict__ emV,
               const float* __restrict__ emS, const float* __restrict__ emA,
               const float* __restrict__ gem, const float* __restrict__ tau,
               const float* __restrict__ dec, const float* __restrict__ wwp,
             float* __restrict__ outK, float* __restrict__ outV,
             float* __restrict__ outS, float* __restrict__ outA,
             float* __restrict__ ws)
{
    const int sb = blockIdx.x; const int m0 = blockIdx.y << 6;
    const int t = threadIdx.x;
    __shared__ float ckn[64][68];
    __shared__ float cvv[64][68];
    __shared__ float alphaT[64][64];   // [c][m]
    __shared__ float apsL[64];
    __shared__ float psum[4][64];
    __shared__ float pn[4][64];
    __shared__ float mx[64], gs[64], Sl[64];

    const float gv  = gem[sb];
    const float invt = 1.0f / fmaxf(tau[sb], 0.01f);
    const float wwv = wwp[sb];
    const float dcv = dec[sb];

    #pragma unroll
    for (int k = 0; k < 4; ++k) {
        const int fid = t + (k << 8);
        const int row = fid >> 4;
        const int col = (fid & 15) << 2;
        *(float4*)&ckn[row][col] = *(const float4*)&ws[WS_CKN + ((size_t)sb*CC + row)*DD + col];
        *(float4*)&cvv[row][col] = *(const float4*)&ws[WS_CV  + ((size_t)sb*CC + row)*DD + col];
    }
    if (t < 64) {
        float mg = -3.0e38f;
        #pragma unroll
        for (int p = 0; p < 16; ++p)
            mg = fmaxf(mg, ws[WS_PMAX + ((size_t)sb*CC + t)*16 + p]);
        float sg = 0.f;
        #pragma unroll
        for (int p = 0; p < 16; ++p)
            sg += ws[WS_PSUM + ((size_t)sb*CC + t)*16 + p] *
                  __expf(ws[WS_PMAX + ((size_t)sb*CC + t)*16 + p] - mg);
        const float cw = ws[WS_CW + sb*CC + t];
        mx[t] = mg;
        gs[t] = gv * cw / sg;
        Sl[t] = emS[(size_t)sb*MM + m0 + t];
    }
    __syncthreads();

    const int m = t & 63, w = t >> 6;

    {
        float acc[16];
        #pragma unroll
        for (int i = 0; i < 16; ++i) acc[i] = 0.f;
        const float* Krow = emK + ((size_t)sb*MM + m0 + m)*DD;
        #pragma unroll 4
        for (int ch = 0; ch < 16; ++ch) {
            const float4 k4 = *(const float4*)&Krow[ch << 2];
            #pragma unroll
            for (int i = 0; i < 16; ++i) {
                const float4 c4 = *(const float4*)&ckn[(w << 4) + i][ch << 2];
                acc[i] = FMA4(k4, c4, acc[i]);
            }
        }
        const float Sv = Sl[m];
        #pragma unroll
        for (int i = 0; i < 16; ++i) {
            const int c = (w << 4) + i;
            const float zz = (acc[i] - wwv*Sv) * invt;
            alphaT[c][m] = gs[c] * __expf(zz - mx[c]);
        }
    }
    __syncthreads();

    {
        float p = 0.f;
        #pragma unroll
        for (int i = 0; i < 16; ++i) p += alphaT[(w << 4) + i][m];
        psum[w][m] = p;
    }
    __syncthreads();
    if (t < 64) apsL[t] = (psum[0][t] + psum[1][t]) + (psum[2][t] + psum[3][t]);
    __syncthreads();

    float bk[16], bv[16];
    #pragma unroll
    for (int i = 0; i < 16; ++i) { bk[i] = 0.f; bv[i] = 0.f; }
    for (int cI = 0; cI < 64; ++cI) {
        const float a = alphaT[cI][m];
        #pragma unroll
        for (int k = 0; k < 4; ++k) {
            const float4 c4 = *(const float4*)&ckn[cI][(w << 4) + (k << 2)];
            const float4 v4 = *(const float4*)&cvv[cI][(w << 4) + (k << 2)];
            bk[(k<<2)+0] = fmaf(a, c4.x, bk[(k<<2)+0]);
            bk[(k<<2)+1] = fmaf(a, c4.y, bk[(k<<2)+1]);
            bk[(k<<2)+2] = fmaf(a, c4.z, bk[(k<<2)+2]);
            bk[(k<<2)+3] = fmaf(a, c4.w, bk[(k<<2)+3]);
            bv[(k<<2)+0] = fmaf(a, v4.x, bv[(k<<2)+0]);
            bv[(k<<2)+1] = fmaf(a, v4.y, bv[(k<<2)+1]);
            bv[(k<<2)+2] = fmaf(a, v4.z, bv[(k<<2)+2]);
            bv[(k<<2)+3] = fmaf(a, v4.w, bv[(k<<2)+3]);
        }
    }

    const float aps = apsL[m];
    const float idn = 1.0f / fmaxf(aps, EPSV);
    float ssq = 0.f;
    #pragma unroll
    for (int i = 0; i < 16; ++i) { bk[i] *= idn; bv[i] *= idn; ssq = fmaf(bk[i], bk[i], ssq); }
    pn[w][m] = ssq;
    __syncthreads();
    const float nrm2 = (pn[0][m] + pn[1][m]) + (pn[2][m] + pn[3][m]);
    const float innv = 1.0f / fmaxf(sqrtf(nrm2), EPSV);
    const float ae = fminf(aps, 1.0f);
    const float oma = 1.0f - ae;
    const bool upd = aps > EPSV;
    const size_t gb = ((size_t)sb*MM + m0 + m)*DD + (w << 4);
    #pragma unroll
    for (int kq = 0; kq < 4; ++kq) {
        const float4 kk = *(const float4*)&emK[gb + (kq << 2)];
        const float4 vv = *(const float4*)&emV[gb + (kq << 2)];
        float4 nk, nv2;
        if (upd) {
            nk.x = oma*kk.x + ae*(bk[(kq<<2)+0]*innv);
            nk.y = oma*kk.y + ae*(bk[(kq<<2)+1]*innv);
            nk.z = oma*kk.z + ae*(bk[(kq<<2)+2]*innv);
            nk.w = oma*kk.w + ae*(bk[(kq<<2)+3]*innv);
            nv2.x = oma*vv.x + ae*bv[(kq<<2)+0];
            nv2.y = oma*vv.y + ae*bv[(kq<<2)+1];
            nv2.z = oma*vv.z + ae*bv[(kq<<2)+2];
            nv2.w = oma*vv.w + ae*bv[(kq<<2)+3];
        } else { nk = kk; nv2 = vv; }
        *(float4*)&outK[gb + (kq << 2)] = nk;
        *(float4*)&outV[gb + (kq << 2)] = nv2;
    }
    if (w == 0) {
        const float pre = fminf(fmaxf(Sl[m] + aps, 0.f), SMAXV) * dcv;
        outS[(size_t)sb*MM + m0 + m] = pre;
        outA[(size_t)sb*MM + m0 + m] = emA[(size_t)sb*MM + m0 + m] * (1.0f - aps);
        float tot = pre;
        #pragma unroll
        for (int off = 32; off >= 1; off >>= 1) tot += __shfl_xor(tot, off, 64);
        if (m == 0) atomicAdd(&ws[WS_TOTS + sb], tot);
    }
}

// ---------------------------------------------------------------------------
// Kernel 4: budget rescale of new_S
// ---------------------------------------------------------------------------
__global__ __launch_bounds__(256)
void k4_budget(float* __restrict__ outS, const float* __restrict__ ws)
{
    const int sb = blockIdx.x;
    const float sc = fminf(1.0f, BUDGETV / (ws[WS_TOTS + sb] + EPSV));
    for (int m = threadIdx.x; m < MM; m += 256)
        outS[(size_t)sb*MM + m] *= sc;
}

extern "C" void kernel_launch(void* const* d_in, const int* in_sizes, int n_in,
                              void* d_out, int out_size, void* d_ws, size_t ws_size,
                              hipStream_t stream)
{
    const float* q   = (const float*)d_in[0];
    const float* qnv = (const float*)d_in[1];
    const float* vnv = (const float*)d_in[2];
    const float* sur = (const float*)d_in[3];
    const float* wn  = (const float*)d_in[4];
    const float* gem = (const float*)d_in[5];
    const float* tau = (const float*)d_in[6];
    const float* dec = (const float*)d_in[7];
    const float* wwp = (const float*)d_in[8];
    const float* emK = (const float*)d_in[9];
    const float* emV = (const float*)d_in[10];
    const float* emS = (const float*)d_in[11];
    const float* emA = (const float*)d_in[12];

    float* out  = (float*)d_out;
    float* outK = out + 2097152;
    float* outV = out + 6291456;
    float* outS = out + 10485760;
    float* outA = out + 10551296;
    float* ws = (float*)d_ws;

    // f16 copy of emK lives in the outV output region (k3c rewrites it later)
    unsigned short* Kh = (unsigned short*)outV;

    hipMemsetAsync((char*)d_ws + WS_TOTS*sizeof(float), 0, 32*sizeof(float), stream);

    k0_cvt<<<2048, 256, 0, stream>>>(emK, Kh);
    k1_read<<<dim3(32, 16), 256, 0, stream>>>(q, qnv, sur, wn, emK, Kh, emV, emS, out, ws);
    k2_topc<<<32, 64, 0, stream>>>(ws);
    k3a_gather<<<32, 256, 0, stream>>>(qnv, vnv, ws);
    k3b_stats<<<dim3(32, 16), 256, 0, stream>>>(emK, emS, tau, wwp, ws);
    k3c_write<<<dim3(32, 32), 256, 0, stream>>>(emK, emV, emS, emA, gem, tau, dec, wwp,
                                                outK, outV, outS, outA, ws);
    k4_budget<<<32, 256, 0, stream>>>(outS, ws);
}